// Round 13
// baseline (1771.602 us; speedup 1.0000x reference)
//
#include <hip/hip_runtime.h>
#include <hip/hip_bf16.h>

#define ALPHA 1.702f
#define GLIMIT 7.0f

typedef __attribute__((ext_vector_type(4))) float f32x4;
typedef __attribute__((ext_vector_type(4))) short short4v;
typedef __attribute__((ext_vector_type(8))) __bf16 bf16x8;
typedef __attribute__((ext_vector_type(8))) short short8;

typedef __attribute__((address_space(3))) unsigned int as3_uint;
typedef const __attribute__((address_space(1))) unsigned int as1_uint;

__device__ __forceinline__ void async_copy16(void* lds, const void* g) {
    __builtin_amdgcn_global_load_lds((as1_uint*)g, (as3_uint*)lds, 16, 0, 0);
}

__device__ __forceinline__ short f2bf(float f) {
    unsigned u = __float_as_uint(f);
    unsigned r = (u + 0x7fffu + ((u >> 16) & 1u)) >> 16;
    return (short)r;
}

// ---------- fp32 -> bf16 straight convert (x) ----------
__global__ void cvt_bf16_kernel(const float* __restrict__ src,
                                short* __restrict__ dst, int n4) {
    int i = blockIdx.x * blockDim.x + threadIdx.x;
    if (i < n4) {
        float4 v = reinterpret_cast<const float4*>(src)[i];
        short4 o;
        o.x = f2bf(v.x); o.y = f2bf(v.y); o.z = f2bf(v.z); o.w = f2bf(v.w);
        reinterpret_cast<short4*>(dst)[i] = o;
    }
}

// ---------- fp32 [z][R][C] -> bf16 [z][C][R] transpose-convert ----------
// perm!=0: pair-split permutation within each 256-row panel of dst:
// row rloc -> (rloc&1)*128 + (rloc>>1).
__global__ void transpose_cvt(const float* __restrict__ src,
                              short* __restrict__ dst, int R, int C, int perm) {
    __shared__ float t[64][65];
    const int z  = blockIdx.z;
    const int c0 = blockIdx.x * 64;
    const int r0 = blockIdx.y * 64;
    const float* s = src + (size_t)z * R * C;
    short* d = dst + (size_t)z * R * C;
    const int tid = threadIdx.x;
#pragma unroll
    for (int i = 0; i < 16; ++i) {
        int idx = i * 256 + tid;
        int r = idx >> 6, c = idx & 63;
        t[r][c] = s[(size_t)(r0 + r) * C + c0 + c];
    }
    __syncthreads();
#pragma unroll
    for (int i = 0; i < 16; ++i) {
        int idx = i * 256 + tid;
        int r = idx >> 6, c = idx & 63;
        int rr = c0 + r;
        int rloc = rr & 255;
        int rp = perm ? ((rr & ~255) | ((rloc & 1) << 7) | (rloc >> 1)) : rr;
        d[(size_t)rp * R + r0 + c] = f2bf(t[c][r]);
    }
}

// =================== 256x256 8-phase GEMM core ==========

struct Gemm1TSrc {
    const short* A; const short* B;
    __device__ __forceinline__ const short* operator()(int t, int h) const {
        int e = (t >> 5) & 7;
        size_t ko = (size_t)(t & 31) << 6;
        if (h & 2) return B + ((size_t)(h & 1) << 18) + ko;
        return A + ((size_t)e << 23) + ((size_t)(h & 1) << 18) + ko;
    }
};

struct Gemm2Src {
    const short* act; const short* wdt; size_t aoff, boff; int kh;
    __device__ __forceinline__ const short* operator()(int t, int h) const {
        int g = (kh << 7) + t;
        int e = (g >> 5) & 7;
        size_t ko = (size_t)(g & 31) << 6;
        if (h & 2) return wdt + ((size_t)e << 22) + boff + ((size_t)(h & 1) << 18) + ko;
        return act + ((size_t)e << 23) + aoff + ((size_t)(h & 1) << 18) + ko;
    }
};

#define PH_BAR()  __builtin_amdgcn_s_barrier()
#define PH_LGKM() do { asm volatile("s_waitcnt lgkmcnt(0)" ::: "memory"); \
                       __builtin_amdgcn_sched_barrier(0); } while (0)
#define VMW(n)    asm volatile("s_waitcnt vmcnt(" #n ")" ::: "memory")

template <int NT, int SEG, bool DRAIN, typename Src, typename Epi>
__device__ __forceinline__ void gemm_8phase(const Src& src, char* smem,
                                            f32x4 (&acc)[8][4], const Epi& epi) {
    const int tid  = threadIdx.x;
    const int lane = tid & 63;
    const int wid  = tid >> 6;
    const int wr   = wid >> 2;
    const int wcol = wid & 3;
    const int lhi  = lane >> 4;
    const int llo  = lane & 15;

    auto stage = [&](int buf, int h, const short* g) {
        char* dst = smem + buf * 65536 + h * 16384;
        {
            int c = tid, r = c >> 3, s = (c & 7) ^ (r & 7);
            async_copy16(dst + c * 16, g + (size_t)r * 2048 + s * 8);
        }
        {
            int c = tid + 512, r = c >> 3, s = (c & 7) ^ (r & 7);
            async_copy16(dst + c * 16, g + (size_t)r * 2048 + s * 8);
        }
    };
    auto ldfrag = [&](int buf, int h, int row, int slot) {
        return *(const bf16x8*)(smem + buf * 65536 + h * 16384 + row * 128 +
                                ((slot ^ (row & 7)) << 4));
    };

    stage(0, 0, src(0, 0)); stage(0, 2, src(0, 2));
    stage(0, 3, src(0, 3)); stage(0, 1, src(0, 1));
    stage(1, 0, src(1, 0)); stage(1, 2, src(1, 2)); stage(1, 3, src(1, 3));
    VMW(8);
    PH_BAR();

    bf16x8 a[4][2], b[4][2];
#pragma unroll
    for (int n = 0; n < 2; ++n) {
        int row = wcol * 32 + n * 16 + llo;
        b[n][0] = ldfrag(0, 2, row, lhi);
        b[n][1] = ldfrag(0, 2, row, 4 + lhi);
    }

    for (int t = 0; t < NT; ++t) {
        const int cur = t & 1, nxt = cur ^ 1;
        // P0
#pragma unroll
        for (int m = 0; m < 4; ++m) {
            int row = wr * 64 + m * 16 + llo;
            a[m][0] = ldfrag(cur, 0, row, lhi);
            a[m][1] = ldfrag(cur, 0, row, 4 + lhi);
        }
        if (t + 1 < NT) stage(nxt, 1, src(t + 1, 1));
        PH_BAR(); PH_LGKM();
        __builtin_amdgcn_s_setprio(1);
#pragma unroll
        for (int m = 0; m < 4; ++m)
#pragma unroll
            for (int n = 0; n < 2; ++n)
#pragma unroll
                for (int ks = 0; ks < 2; ++ks)
                    acc[m][n] = __builtin_amdgcn_mfma_f32_16x16x32_bf16(
                        a[m][ks], b[n][ks], acc[m][n], 0, 0, 0);
        __builtin_amdgcn_s_setprio(0);
        PH_BAR();
        // P1
#pragma unroll
        for (int n = 0; n < 2; ++n) {
            int row = wcol * 32 + n * 16 + llo;
            b[2 + n][0] = ldfrag(cur, 3, row, lhi);
            b[2 + n][1] = ldfrag(cur, 3, row, 4 + lhi);
        }
        if (t + 2 < NT) { stage(cur, 0, src(t + 2, 0)); VMW(10); }
        else if (t + 1 < NT) { VMW(8); }
        else { VMW(0); }
        PH_BAR(); PH_LGKM();
        __builtin_amdgcn_s_setprio(1);
#pragma unroll
        for (int m = 0; m < 4; ++m)
#pragma unroll
            for (int n = 2; n < 4; ++n)
#pragma unroll
                for (int ks = 0; ks < 2; ++ks)
                    acc[m][n] = __builtin_amdgcn_mfma_f32_16x16x32_bf16(
                        a[m][ks], b[n][ks], acc[m][n], 0, 0, 0);
        __builtin_amdgcn_s_setprio(0);
        PH_BAR();
        // P2
#pragma unroll
        for (int m = 0; m < 4; ++m) {
            int row = wr * 64 + m * 16 + llo;
            a[m][0] = ldfrag(cur, 1, row, lhi);
            a[m][1] = ldfrag(cur, 1, row, 4 + lhi);
        }
        if (t + 2 < NT) stage(cur, 2, src(t + 2, 2));
        PH_BAR(); PH_LGKM();
        __builtin_amdgcn_s_setprio(1);
#pragma unroll
        for (int m = 0; m < 4; ++m)
#pragma unroll
            for (int n = 0; n < 2; ++n)
#pragma unroll
                for (int ks = 0; ks < 2; ++ks)
                    acc[4 + m][n] = __builtin_amdgcn_mfma_f32_16x16x32_bf16(
                        a[m][ks], b[n][ks], acc[4 + m][n], 0, 0, 0);
        __builtin_amdgcn_s_setprio(0);
        PH_BAR();
        // P3
        if (t + 2 < NT) { stage(cur, 3, src(t + 2, 3)); VMW(8); }
        else if (t + 1 < NT) { VMW(2); }
        else { VMW(0); }
        PH_BAR(); PH_LGKM();
        __builtin_amdgcn_s_setprio(1);
        if (t + 1 < NT) {
#pragma unroll
            for (int n = 0; n < 2; ++n) {
                int row = wcol * 32 + n * 16 + llo;
                b[n][0] = ldfrag(nxt, 2, row, lhi);
                b[n][1] = ldfrag(nxt, 2, row, 4 + lhi);
            }
        }
#pragma unroll
        for (int m = 0; m < 4; ++m)
#pragma unroll
            for (int n = 2; n < 4; ++n)
#pragma unroll
                for (int ks = 0; ks < 2; ++ks)
                    acc[4 + m][n] = __builtin_amdgcn_mfma_f32_16x16x32_bf16(
                        a[m][ks], b[n][ks], acc[4 + m][n], 0, 0, 0);
        __builtin_amdgcn_s_setprio(0);
        PH_BAR();
        if (((t + 1) & (SEG - 1)) == 0) {
            epi(t / SEG, acc);
            if (t + 1 < NT) {
                if (DRAIN) { VMW(0); }
#pragma unroll
                for (int m = 0; m < 8; ++m)
#pragma unroll
                    for (int n = 0; n < 4; ++n)
                        acc[m][n] = (f32x4){0.f, 0.f, 0.f, 0.f};
            }
        }
    }
}

// ---------- GEMM1-T body (SEG templated: 32 = real, 256 = no-mid-epi diag) ----
template <int SEG>
__device__ __forceinline__ void gemm1_body_T(
    const short* __restrict__ xb, const short* __restrict__ wgutp,
    const float* __restrict__ bias, const float* __restrict__ rwp,
    short* __restrict__ act) {
    __shared__ __align__(16) char smem[131072];
    __shared__ float rws2[2048];
    __shared__ float bias2[2048];
    const int bid = blockIdx.x;
    const int xcd = bid & 7, j = bid >> 3;
    const int t0 = (((xcd & 3) << 2) + (j & 3)) << 8;
    const int p0 = (((xcd >> 2) << 3) + (j >> 2)) << 8;
    const int tid  = threadIdx.x;
    const int lane = tid & 63;
    const int wid  = tid >> 6;
    const int wr = wid >> 2, wcol = wid & 3;
    const int lhi = lane >> 4, llo = lane & 15;

    ((float4*)rws2)[tid] = ((const float4*)(rwp + (size_t)t0 * 8))[tid];
    {
        int idx = tid << 2;
        int ei = idx >> 8, c = idx & 255;
        ((float4*)bias2)[tid] =
            *(const float4*)(bias + (size_t)ei * 4096 + p0 + c);
    }

    f32x4 acc[8][4];
#pragma unroll
    for (int m = 0; m < 8; ++m)
#pragma unroll
        for (int n = 0; n < 4; ++n) acc[m][n] = (f32x4){0.f, 0.f, 0.f, 0.f};

    Gemm1TSrc src{ wgutp + (size_t)p0 * 2048, xb + (size_t)t0 * 2048 };
    const int dbase = (p0 >> 1) + wr * 64;

    auto epi = [&](int s, f32x4 (&ac)[8][4]) {
        int e = s & 7;
        short* acte = act + ((size_t)e << 23);
#pragma unroll
        for (int m = 0; m < 4; ++m) {
            float bg[4], bu[4];
#pragma unroll
            for (int q = 0; q < 4; ++q) {
                int jj = wr * 64 + m * 16 + (lhi << 2) + q;
                bg[q] = bias2[(e << 8) + 2 * jj];
                bu[q] = bias2[(e << 8) + 2 * jj + 1];
            }
            int dc0 = dbase + m * 16 + (lhi << 2);
#pragma unroll
            for (int n = 0; n < 4; ++n) {
                int tloc = ((n >> 1) << 7) + wcol * 32 + ((n & 1) << 4) + llo;
                float w = rws2[tloc * 8 + e];
                short4v o;
#pragma unroll
                for (int q = 0; q < 4; ++q) {
                    float g = ac[m][n][q] + bg[q];
                    float u = ac[4 + m][n][q] + bu[q];
                    g = fminf(g, GLIMIT);
                    u = fmaxf(fminf(u, GLIMIT), -GLIMIT);
                    float glu = g / (1.f + __expf(-ALPHA * g));
                    o[q] = f2bf((u + 1.f) * glu * w);
                }
                __builtin_nontemporal_store(
                    o, (short4v*)(acte + (size_t)(t0 + tloc) * 2048 + dc0));
            }
        }
    };
    gemm_8phase<256, SEG, true>(src, smem, acc, epi);
}

__global__ __launch_bounds__(512, 2) void gemm1_main(
    const short* xb, const short* wgutp, const float* bias, const float* rwp,
    short* act) { gemm1_body_T<32>(xb, wgutp, bias, rwp, act); }

// DIAG: identical loop, zero mid-loop epilogues (single final epi). Measures L.
__global__ __launch_bounds__(512, 2) void gemm1_noepi(
    const short* xb, const short* wgutp, const float* bias, const float* rwp,
    short* act) { gemm1_body_T<256>(xb, wgutp, bias, rwp, act); }

// ---------- GEMM2 body (NTT templated: 128 = real split-K, 256 = diag) -------
template <int NTT>
__device__ __forceinline__ void gemm2_body(
    const short* __restrict__ act, const short* __restrict__ wdt,
    float* __restrict__ dst, int kh) {
    __shared__ __align__(16) char smem[131072];
    int flat = blockIdx.x + (blockIdx.y << 3);
    int swz = (flat & 7) * 16 + (flat >> 3);
    const int n0 = (swz & 7) * 256;
    const int m0 = (swz >> 3) * 256;
    const int tid  = threadIdx.x;
    const int lane = tid & 63;
    const int wid  = tid >> 6;
    const int wr = wid >> 2, wcol = wid & 3;

    f32x4 acc[8][4];
#pragma unroll
    for (int m = 0; m < 8; ++m)
#pragma unroll
        for (int n = 0; n < 4; ++n) acc[m][n] = (f32x4){0.f, 0.f, 0.f, 0.f};

    Gemm2Src src{ act, wdt, (size_t)m0 * 2048, (size_t)n0 * 2048, kh };

    auto epi = [&](int, f32x4 (&ac)[8][4]) {
#pragma unroll
        for (int m = 0; m < 8; ++m) {
            int row = m0 + (m >> 2) * 128 + wr * 64 + (m & 3) * 16 + ((lane >> 4) << 2);
#pragma unroll
            for (int n = 0; n < 4; ++n) {
                int col = n0 + (n >> 1) * 128 + wcol * 32 + (n & 1) * 16 + (lane & 15);
#pragma unroll
                for (int q = 0; q < 4; ++q)
                    dst[(size_t)(row + q) * 2048 + col] = ac[m][n][q];
            }
        }
    };
    gemm_8phase<NTT, NTT, false>(src, smem, acc, epi);
}

__global__ __launch_bounds__(512, 2) void gemm2_8ph(
    const short* act, const short* wdt, float* out, float* part) {
    gemm2_body<128>(act, wdt, (blockIdx.z == 0) ? out : part, blockIdx.z);
}

// DIAG: full-K (NT=256), one epilogue -> gemm2 steady rate, top-5-visible.
__global__ __launch_bounds__(512, 2) void gemm2_long(
    const short* act, const short* wdt, float* part) {
    gemm2_body<256>(act, wdt, part, 0);
}

// ---------- reduce: out += partial + sum_e rw[t,e]*bd[e,h] ----------
__global__ __launch_bounds__(256) void reduce_bias(
    const float* __restrict__ p1, const float* __restrict__ rw,
    const float* __restrict__ bd, float* __restrict__ out) {
    const int t = blockIdx.x;
    const int tid = threadIdx.x;
    float rwv[8];
#pragma unroll
    for (int e = 0; e < 8; ++e) rwv[e] = rw[(size_t)t * 8 + e];
    size_t base = (size_t)t * 2048;
#pragma unroll
    for (int i = 0; i < 2; ++i) {
        int h = (tid + i * 256) * 4;
        f32x4 o = *(const f32x4*)(out + base + h);
        f32x4 p = *(const f32x4*)(p1 + base + h);
        o += p;
#pragma unroll
        for (int e = 0; e < 8; ++e) {
            f32x4 bb = *(const f32x4*)(bd + e * 2048 + h);
            o += rwv[e] * bb;
        }
        *(f32x4*)(out + base + h) = o;
    }
}

extern "C" void kernel_launch(void* const* d_in, const int* in_sizes, int n_in,
                              void* d_out, int out_size, void* d_ws, size_t ws_size,
                              hipStream_t stream) {
    const float* x   = (const float*)d_in[0];
    const float* wgu = (const float*)d_in[1];
    const float* bgu = (const float*)d_in[2];
    const float* wd  = (const float*)d_in[3];
    const float* bd  = (const float*)d_in[4];
    const float* rw  = (const float*)d_in[5];
    float* out = (float*)d_out;

    char* ws = (char*)d_ws;
    short* xb   = (short*)(ws);
    short* wgut = (short*)(ws + 16777216);
    float* p1   = (float*)(ws + 16777216);   // aliases wgut (dead after gemm1)
    short* wdt  = (short*)(ws + 150994944);
    short* actb = (short*)(ws + 218103808);

    cvt_bf16_kernel<<<8192, 256, 0, stream>>>(x, xb, 2097152);
    transpose_cvt<<<dim3(64, 32, 8), 256, 0, stream>>>(wgu, wgut, 2048, 4096, 1);
    transpose_cvt<<<dim3(32, 32, 8), 256, 0, stream>>>(wd, wdt, 2048, 2048, 0);
    gemm1_main<<<256, 512, 0, stream>>>(xb, wgut, bgu, rw, actb);
    gemm2_8ph<<<dim3(8, 16, 2), 512, 0, stream>>>(actb, wdt, out, p1);
    reduce_bias<<<4096, 256, 0, stream>>>(p1, rw, bd, out);

    // ---- diagnostics (run AFTER real pipeline; actb/p1 fully rewritten by
    // the real kernels at the start of every call -> deterministic output) ----
    gemm1_noepi<<<256, 512, 0, stream>>>(xb, wgut, bgu, rw, actb);
    gemm2_long<<<dim3(8, 16, 1), 512, 0, stream>>>(actb, wdt, p1);
}

// Round 14
// 908.659 us; speedup vs baseline: 1.9497x; 1.9497x over previous
//
#include <hip/hip_runtime.h>
#include <hip/hip_bf16.h>

#define ALPHA 1.702f
#define GLIMIT 7.0f

typedef __attribute__((ext_vector_type(4))) float f32x4;
typedef __attribute__((ext_vector_type(4))) short short4v;
typedef __attribute__((ext_vector_type(8))) __bf16 bf16x8;
typedef __attribute__((ext_vector_type(8))) short short8;

typedef __attribute__((address_space(3))) unsigned int as3_uint;
typedef const __attribute__((address_space(1))) unsigned int as1_uint;

__device__ __forceinline__ void async_copy16(void* lds, const void* g) {
    __builtin_amdgcn_global_load_lds((as1_uint*)g, (as3_uint*)lds, 16, 0, 0);
}

__device__ __forceinline__ short f2bf(float f) {
    unsigned u = __float_as_uint(f);
    unsigned r = (u + 0x7fffu + ((u >> 16) & 1u)) >> 16;
    return (short)r;
}

// ---------- fp32 -> bf16 straight convert (x) ----------
__global__ void cvt_bf16_kernel(const float* __restrict__ src,
                                short* __restrict__ dst, int n4) {
    int i = blockIdx.x * blockDim.x + threadIdx.x;
    if (i < n4) {
        float4 v = reinterpret_cast<const float4*>(src)[i];
        short4 o;
        o.x = f2bf(v.x); o.y = f2bf(v.y); o.z = f2bf(v.z); o.w = f2bf(v.w);
        reinterpret_cast<short4*>(dst)[i] = o;
    }
}

// ---------- fp32 [z][R][C] -> bf16 [z][C][R] transpose-convert ----------
// perm!=0: pair-split permutation within each 256-row panel of dst:
// row rloc -> (rloc&1)*128 + (rloc>>1).
__global__ void transpose_cvt(const float* __restrict__ src,
                              short* __restrict__ dst, int R, int C, int perm) {
    __shared__ float t[64][65];
    const int z  = blockIdx.z;
    const int c0 = blockIdx.x * 64;
    const int r0 = blockIdx.y * 64;
    const float* s = src + (size_t)z * R * C;
    short* d = dst + (size_t)z * R * C;
    const int tid = threadIdx.x;
#pragma unroll
    for (int i = 0; i < 16; ++i) {
        int idx = i * 256 + tid;
        int r = idx >> 6, c = idx & 63;
        t[r][c] = s[(size_t)(r0 + r) * C + c0 + c];
    }
    __syncthreads();
#pragma unroll
    for (int i = 0; i < 16; ++i) {
        int idx = i * 256 + tid;
        int r = idx >> 6, c = idx & 63;
        int rr = c0 + r;
        int rloc = rr & 255;
        int rp = perm ? ((rr & ~255) | ((rloc & 1) << 7) | (rloc >> 1)) : rr;
        d[(size_t)rp * R + r0 + c] = f2bf(t[c][r]);
    }
}

// =================== 256x256 8-phase GEMM core (A1 2-deep) ==========
// LDS slots: A0[2]@0 | B0[2]@32K | B1[2]@64K | A1[3]@96K = 147456 B.
// Per step all four half-tiles of t+2 are staged (uniform bunch);
// single VMW(8) at P3 forces bunch(t+1) -> 4-7 phase cover for every tile.
// No per-step P1 vmcnt. All slot overwrites are barrier-protected.

#define SLOT_A0(p) ((p) * 16384)
#define SLOT_B0(p) (32768 + (p) * 16384)
#define SLOT_B1(p) (65536 + (p) * 16384)
#define SLOT_A1(r) (98304 + (r) * 16384)

struct Gemm1TSrc {
    const short* A; const short* B;
    __device__ __forceinline__ const short* operator()(int t, int h) const {
        int e = (t >> 5) & 7;
        size_t ko = (size_t)(t & 31) << 6;
        if (h & 2) return B + ((size_t)(h & 1) << 18) + ko;
        return A + ((size_t)e << 23) + ((size_t)(h & 1) << 18) + ko;
    }
};

struct Gemm2Src {
    const short* act; const short* wdt; size_t aoff, boff; int kh;
    __device__ __forceinline__ const short* operator()(int t, int h) const {
        int g = (kh << 7) + t;
        int e = (g >> 5) & 7;
        size_t ko = (size_t)(g & 31) << 6;
        if (h & 2) return wdt + ((size_t)e << 22) + boff + ((size_t)(h & 1) << 18) + ko;
        return act + ((size_t)e << 23) + aoff + ((size_t)(h & 1) << 18) + ko;
    }
};

#define PH_BAR()  __builtin_amdgcn_s_barrier()
#define PH_LGKM() do { asm volatile("s_waitcnt lgkmcnt(0)" ::: "memory"); \
                       __builtin_amdgcn_sched_barrier(0); } while (0)
#define VMW(n)    asm volatile("s_waitcnt vmcnt(" #n ")" ::: "memory")

template <int NT, int SEG, bool DRAIN, typename Src, typename Epi>
__device__ __forceinline__ void gemm_8phase(const Src& src, char* smem,
                                            f32x4 (&acc)[8][4], const Epi& epi) {
    const int tid  = threadIdx.x;
    const int lane = tid & 63;
    const int wid  = tid >> 6;
    const int wr   = wid >> 2;
    const int wcol = wid & 3;
    const int lhi  = lane >> 4;
    const int llo  = lane & 15;

    auto stage = [&](int off, const short* g) {
        char* dst = smem + off;
        {
            int c = tid, r = c >> 3, s = (c & 7) ^ (r & 7);
            async_copy16(dst + c * 16, g + (size_t)r * 2048 + s * 8);
        }
        {
            int c = tid + 512, r = c >> 3, s = (c & 7) ^ (r & 7);
            async_copy16(dst + c * 16, g + (size_t)r * 2048 + s * 8);
        }
    };
    auto ldfrag = [&](int off, int row, int slot) {
        return *(const bf16x8*)(smem + off + row * 128 +
                                ((slot ^ (row & 7)) << 4));
    };

    // prologue: bunches for t=0 and t=1 (A0,B0,B1,A1 each)
    stage(SLOT_A0(0), src(0, 0)); stage(SLOT_B0(0), src(0, 2));
    stage(SLOT_B1(0), src(0, 3)); stage(SLOT_A1(0), src(0, 1));
    stage(SLOT_A0(1), src(1, 0)); stage(SLOT_B0(1), src(1, 2));
    stage(SLOT_B1(1), src(1, 3)); stage(SLOT_A1(1), src(1, 1));
    VMW(8);           // forces bunch(0); bunch(1) in flight
    PH_BAR();

    bf16x8 a[4][2], b[4][2];
    // peel: B0(0) -> b[0..1]
#pragma unroll
    for (int n = 0; n < 2; ++n) {
        int row = wcol * 32 + n * 16 + llo;
        b[n][0] = ldfrag(SLOT_B0(0), row, lhi);
        b[n][1] = ldfrag(SLOT_B0(0), row, 4 + lhi);
    }

    int a1s = 0;   // t % 3
    for (int t = 0; t < NT; ++t) {
        const int cur = t & 1, nxt = cur ^ 1;
        const int a1t = (a1s >= 1) ? a1s - 1 : a1s + 2;   // (t+2) % 3
        // ---- P0: read A0(t); stage A1(t+2); MFMA (mh0,nh0) ----
#pragma unroll
        for (int m = 0; m < 4; ++m) {
            int row = wr * 64 + m * 16 + llo;
            a[m][0] = ldfrag(SLOT_A0(cur), row, lhi);
            a[m][1] = ldfrag(SLOT_A0(cur), row, 4 + lhi);
        }
        if (t + 2 < NT) stage(SLOT_A1(a1t), src(t + 2, 1));
        PH_BAR(); PH_LGKM();
        __builtin_amdgcn_s_setprio(1);
#pragma unroll
        for (int m = 0; m < 4; ++m)
#pragma unroll
            for (int n = 0; n < 2; ++n)
#pragma unroll
                for (int ks = 0; ks < 2; ++ks)
                    acc[m][n] = __builtin_amdgcn_mfma_f32_16x16x32_bf16(
                        a[m][ks], b[n][ks], acc[m][n], 0, 0, 0);
        __builtin_amdgcn_s_setprio(0);
        PH_BAR();
        // ---- P1: read B1(t); stage A0(t+2); MFMA (mh0,nh1) ----
#pragma unroll
        for (int n = 0; n < 2; ++n) {
            int row = wcol * 32 + n * 16 + llo;
            b[2 + n][0] = ldfrag(SLOT_B1(cur), row, lhi);
            b[2 + n][1] = ldfrag(SLOT_B1(cur), row, 4 + lhi);
        }
        if (t + 2 < NT) stage(SLOT_A0(cur), src(t + 2, 0));
        PH_BAR(); PH_LGKM();
        __builtin_amdgcn_s_setprio(1);
#pragma unroll
        for (int m = 0; m < 4; ++m)
#pragma unroll
            for (int n = 2; n < 4; ++n)
#pragma unroll
                for (int ks = 0; ks < 2; ++ks)
                    acc[m][n] = __builtin_amdgcn_mfma_f32_16x16x32_bf16(
                        a[m][ks], b[n][ks], acc[m][n], 0, 0, 0);
        __builtin_amdgcn_s_setprio(0);
        PH_BAR();
        // ---- P2: read A1(t); stage B0(t+2); MFMA (mh1,nh0) ----
#pragma unroll
        for (int m = 0; m < 4; ++m) {
            int row = wr * 64 + m * 16 + llo;
            a[m][0] = ldfrag(SLOT_A1(a1s), row, lhi);
            a[m][1] = ldfrag(SLOT_A1(a1s), row, 4 + lhi);
        }
        if (t + 2 < NT) stage(SLOT_B0(cur), src(t + 2, 2));
        PH_BAR(); PH_LGKM();
        __builtin_amdgcn_s_setprio(1);
#pragma unroll
        for (int m = 0; m < 4; ++m)
#pragma unroll
            for (int n = 0; n < 2; ++n)
#pragma unroll
                for (int ks = 0; ks < 2; ++ks)
                    acc[4 + m][n] = __builtin_amdgcn_mfma_f32_16x16x32_bf16(
                        a[m][ks], b[n][ks], acc[4 + m][n], 0, 0, 0);
        __builtin_amdgcn_s_setprio(0);
        PH_BAR();
        // ---- P3: stage B1(t+2); VMW(8); read B0(t+1); MFMA (mh1,nh1) ----
        if (t + 2 < NT) { stage(SLOT_B1(cur), src(t + 2, 3)); VMW(8); }
        else { VMW(0); }
        PH_BAR(); PH_LGKM();
        __builtin_amdgcn_s_setprio(1);
        if (t + 1 < NT) {
#pragma unroll
            for (int n = 0; n < 2; ++n) {
                int row = wcol * 32 + n * 16 + llo;
                b[n][0] = ldfrag(SLOT_B0(nxt), row, lhi);
                b[n][1] = ldfrag(SLOT_B0(nxt), row, 4 + lhi);
            }
        }
#pragma unroll
        for (int m = 0; m < 4; ++m)
#pragma unroll
            for (int n = 2; n < 4; ++n)
#pragma unroll
                for (int ks = 0; ks < 2; ++ks)
                    acc[4 + m][n] = __builtin_amdgcn_mfma_f32_16x16x32_bf16(
                        a[m][ks], b[n][ks], acc[4 + m][n], 0, 0, 0);
        __builtin_amdgcn_s_setprio(0);
        PH_BAR();
        // ---- segment boundary ----
        if (((t + 1) & (SEG - 1)) == 0) {
            epi(t / SEG, acc);
            if (t + 1 < NT) {
                if (DRAIN) { VMW(0); }
#pragma unroll
                for (int m = 0; m < 8; ++m)
#pragma unroll
                    for (int n = 0; n < 4; ++n)
                        acc[m][n] = (f32x4){0.f, 0.f, 0.f, 0.f};
            }
        }
        a1s = (a1s == 2) ? 0 : a1s + 1;
    }
}

// ---------- GEMM1-T (persistent): output-transposed, lane-local GEGLU ----------
__global__ __launch_bounds__(512, 2) void gemm1_main(
    const short* __restrict__ xb, const short* __restrict__ wgutp,
    const float* __restrict__ bias, const float* __restrict__ rwp,
    short* __restrict__ act) {
    __shared__ __align__(16) char smem[147456];
    const int bid = blockIdx.x;
    const int xcd = bid & 7, j = bid >> 3;
    const int t0 = (((xcd & 3) << 2) + (j & 3)) << 8;      // token tile
    const int p0 = (((xcd >> 2) << 3) + (j >> 2)) << 8;    // gate_up row panel
    const int tid  = threadIdx.x;
    const int lane = tid & 63;
    const int wid  = tid >> 6;
    const int wr = wid >> 2, wcol = wid & 3;
    const int lhi = lane >> 4, llo = lane & 15;

    f32x4 acc[8][4];
#pragma unroll
    for (int m = 0; m < 8; ++m)
#pragma unroll
        for (int n = 0; n < 4; ++n) acc[m][n] = (f32x4){0.f, 0.f, 0.f, 0.f};

    Gemm1TSrc src{ wgutp + (size_t)p0 * 2048, xb + (size_t)t0 * 2048 };
    const int dbase = (p0 >> 1) + wr * 64;

    auto epi = [&](int s, f32x4 (&ac)[8][4]) {
        int e = s & 7;
        short* acte = act + ((size_t)e << 23);
        const float* be = bias + ((size_t)e << 12) + p0;
#pragma unroll
        for (int m = 0; m < 4; ++m) {
            float bg[4], bu[4];
#pragma unroll
            for (int q = 0; q < 4; ++q) {
                int jj = wr * 64 + m * 16 + (lhi << 2) + q;
                bg[q] = be[2 * jj];
                bu[q] = be[2 * jj + 1];
            }
            int dc0 = dbase + m * 16 + (lhi << 2);
#pragma unroll
            for (int n = 0; n < 4; ++n) {
                int tloc = ((n >> 1) << 7) + wcol * 32 + ((n & 1) << 4) + llo;
                float w = rwp[(size_t)(t0 + tloc) * 8 + e];
                short4v o;
#pragma unroll
                for (int q = 0; q < 4; ++q) {
                    float g = ac[m][n][q] + bg[q];
                    float u = ac[4 + m][n][q] + bu[q];
                    g = fminf(g, GLIMIT);
                    u = fmaxf(fminf(u, GLIMIT), -GLIMIT);
                    float glu = g / (1.f + __expf(-ALPHA * g));
                    o[q] = f2bf((u + 1.f) * glu * w);
                }
                __builtin_nontemporal_store(
                    o, (short4v*)(acte + (size_t)(t0 + tloc) * 2048 + dc0));
            }
        }
    };
    gemm_8phase<256, 32, true>(src, smem, acc, epi);
}

// ---------- GEMM2: split-K over experts; kh=0 -> out, kh=1 -> partial ----------
__global__ __launch_bounds__(512, 2) void gemm2_8ph(
    const short* __restrict__ act, const short* __restrict__ wdt,
    float* __restrict__ out, float* __restrict__ part) {
    __shared__ __align__(16) char smem[147456];
    const int kh = blockIdx.z;
    int flat = blockIdx.x + (blockIdx.y << 3);
    int swz = (flat & 7) * 16 + (flat >> 3);
    const int n0 = (swz & 7) * 256;
    const int m0 = (swz >> 3) * 256;
    const int tid  = threadIdx.x;
    const int lane = tid & 63;
    const int wid  = tid >> 6;
    const int wr = wid >> 2, wcol = wid & 3;

    f32x4 acc[8][4];
#pragma unroll
    for (int m = 0; m < 8; ++m)
#pragma unroll
        for (int n = 0; n < 4; ++n) acc[m][n] = (f32x4){0.f, 0.f, 0.f, 0.f};

    Gemm2Src src{ act, wdt, (size_t)m0 * 2048, (size_t)n0 * 2048, kh };
    float* dst = (kh == 0) ? out : part;

    auto epi = [&](int, f32x4 (&ac)[8][4]) {
#pragma unroll
        for (int m = 0; m < 8; ++m) {
            int row = m0 + (m >> 2) * 128 + wr * 64 + (m & 3) * 16 + ((lane >> 4) << 2);
#pragma unroll
            for (int n = 0; n < 4; ++n) {
                int col = n0 + (n >> 1) * 128 + wcol * 32 + (n & 1) * 16 + (lane & 15);
#pragma unroll
                for (int q = 0; q < 4; ++q)
                    dst[(size_t)(row + q) * 2048 + col] = ac[m][n][q];
            }
        }
    };
    gemm_8phase<128, 128, false>(src, smem, acc, epi);
}

// ---------- reduce: out += partial + sum_e rw[t,e]*bd[e,h] ----------
__global__ __launch_bounds__(256) void reduce_bias(
    const float* __restrict__ p1, const float* __restrict__ rw,
    const float* __restrict__ bd, float* __restrict__ out) {
    const int t = blockIdx.x;
    const int tid = threadIdx.x;
    float rwv[8];
#pragma unroll
    for (int e = 0; e < 8; ++e) rwv[e] = rw[(size_t)t * 8 + e];
    size_t base = (size_t)t * 2048;
#pragma unroll
    for (int i = 0; i < 2; ++i) {
        int h = (tid + i * 256) * 4;
        f32x4 o = *(const f32x4*)(out + base + h);
        f32x4 p = *(const f32x4*)(p1 + base + h);
        o += p;
#pragma unroll
        for (int e = 0; e < 8; ++e) {
            f32x4 bb = *(const f32x4*)(bd + e * 2048 + h);
            o += rwv[e] * bb;
        }
        *(f32x4*)(out + base + h) = o;
    }
}

extern "C" void kernel_launch(void* const* d_in, const int* in_sizes, int n_in,
                              void* d_out, int out_size, void* d_ws, size_t ws_size,
                              hipStream_t stream) {
    const float* x   = (const float*)d_in[0];
    const float* wgu = (const float*)d_in[1];
    const float* bgu = (const float*)d_in[2];
    const float* wd  = (const float*)d_in[3];
    const float* bd  = (const float*)d_in[4];
    const float* rw  = (const float*)d_in[5];
    float* out = (float*)d_out;

    char* ws = (char*)d_ws;
    short* xb   = (short*)(ws);
    short* wgut = (short*)(ws + 16777216);
    float* p1   = (float*)(ws + 16777216);   // aliases wgut (dead after gemm1)
    short* wdt  = (short*)(ws + 150994944);
    short* actb = (short*)(ws + 218103808);

    cvt_bf16_kernel<<<8192, 256, 0, stream>>>(x, xb, 2097152);
    transpose_cvt<<<dim3(64, 32, 8), 256, 0, stream>>>(wgu, wgut, 2048, 4096, 1);
    transpose_cvt<<<dim3(32, 32, 8), 256, 0, stream>>>(wd, wdt, 2048, 2048, 0);
    gemm1_main<<<256, 512, 0, stream>>>(xb, wgut, bgu, rw, actb);
    gemm2_8ph<<<dim3(8, 16, 2), 512, 0, stream>>>(actb, wdt, out, p1);
    reduce_bias<<<4096, 256, 0, stream>>>(p1, rw, bd, out);
}